// Round 14
// baseline (331.038 us; speedup 1.0000x reference)
//
#include <hip/hip_runtime.h>
#include <stdint.h>

// Problem constants (fixed by the reference)
#define CHARS   10000
#define KPAD    10240   // K padded to multiple of 64
#define HIDDEN  1024
#define OUTPUT  100
#define OPAD    128     // padded output cols for coalesced W2T
#define BATCH   4096
#define MAXLEN  2048

typedef __bf16 bf16_t;
typedef __bf16 bf16x8 __attribute__((ext_vector_type(8)));
typedef __bf16 bf16x4 __attribute__((ext_vector_type(4)));
typedef float  f32x4  __attribute__((ext_vector_type(4)));
typedef uint32_t u32x4 __attribute__((ext_vector_type(4)));

// async global->LDS, 16B per lane; LDS dst = wave-uniform base + lane*16 (linear)
__device__ __forceinline__ void gload16(const bf16_t* g, bf16_t* l) {
    __builtin_amdgcn_global_load_lds(
        (__attribute__((address_space(1))) void*)const_cast<bf16_t*>(g),
        (__attribute__((address_space(3))) void*)l, 16, 0, 0);
}

// ---------------------------------------------------------------------------
// Legacy split prep (used only on the chunked fallback path)
// ---------------------------------------------------------------------------
__global__ void k_prep(const float* __restrict__ W1, bf16_t* __restrict__ W1b,
                       const float* __restrict__ W2, float* __restrict__ W2T,
                       const float* __restrict__ b1, float* __restrict__ hid) {
    const int bid = blockIdx.x, tid = threadIdx.x;
    if (bid < 2048) {
        const int row = bid >> 1;
        const int g0  = (bid & 1) * 1280;
        for (int j = 0; j < 5; ++j) {
            int c4 = g0 + j * 256 + tid;
            bf16x4 o;
            if (c4 * 4 < CHARS) {
                f32x4 v = *(const f32x4*)(W1 + (size_t)row * CHARS + (size_t)c4 * 4);
                o[0] = (bf16_t)v[0]; o[1] = (bf16_t)v[1];
                o[2] = (bf16_t)v[2]; o[3] = (bf16_t)v[3];
            } else {
                o[0] = o[1] = o[2] = o[3] = (bf16_t)0.0f;
            }
            *(bf16x4*)(W1b + (size_t)row * KPAD + (size_t)c4 * 4) = o;
        }
    } else if (bid < 2560) {
        int i = (bid - 2048) * 256 + tid;
        int o = i & (OPAD - 1), k = i >> 7;
        W2T[i] = (o < OUTPUT) ? W2[(size_t)o * HIDDEN + k] : 0.0f;
    } else {
        const int M4 = BATCH * HIDDEN / 4;
        for (int i = (bid - 2560) * 256 + tid; i < M4; i += 2048 * 256) {
            int h4 = i & (HIDDEN / 4 - 1);
            ((f32x4*)hid)[i] = ((const f32x4*)b1)[h4];
        }
    }
}

// ---------------------------------------------------------------------------
// Per-row histogram body, u16-packed (R13; neutral vs u32 but keeps LDS low)
// ---------------------------------------------------------------------------
__device__ __forceinline__ void hist_body(uint32_t* h2, const int* __restrict__ words,
                                          bf16_t* __restrict__ hist, int row,
                                          int dstRow, int tid) {
#pragma unroll
    for (int i = 0; i < KPAD / 2 / 4 / 256; ++i)  // 5 iters
        *(u32x4*)(h2 + (i * 256 + tid) * 4) = (u32x4){0u, 0u, 0u, 0u};
    __syncthreads();
    const int* w = words + (size_t)row * MAXLEN;
#pragma unroll
    for (int i = 0; i < MAXLEN / 4 / 256; ++i) {  // 2 iters
        int4 t4 = *(const int4*)(w + (i * 256 + tid) * 4);
        atomicAdd(&h2[t4.x >> 1], 1u << ((t4.x & 1) * 16));
        atomicAdd(&h2[t4.y >> 1], 1u << ((t4.y & 1) * 16));
        atomicAdd(&h2[t4.z >> 1], 1u << ((t4.z & 1) * 16));
        atomicAdd(&h2[t4.w >> 1], 1u << ((t4.w & 1) * 16));
    }
    __syncthreads();
    bf16_t* dst = hist + (size_t)dstRow * KPAD;
#pragma unroll
    for (int i = 0; i < KPAD / 8 / 256; ++i) {    // 5 iters
        int j = (i * 256 + tid) * 8;              // j/2 is 4-aligned -> 16B ok
        u32x4 v = *(const u32x4*)(h2 + (j >> 1));
        bf16x8 o;
#pragma unroll
        for (int q = 0; q < 4; ++q) {
            o[2 * q]     = (bf16_t)(float)(v[q] & 0xffffu);
            o[2 * q + 1] = (bf16_t)(float)(v[q] >> 16);
        }
        *(bf16x8*)(dst + j) = o;
    }
}

__global__ void k_hist(const int* __restrict__ words, bf16_t* __restrict__ hist,
                       int rowStart) {
    __shared__ uint32_t h2[KPAD / 2];         // 20 KB
    hist_body(h2, words, hist, rowStart + blockIdx.x, blockIdx.x, threadIdx.x);
}

// ---------------------------------------------------------------------------
// Merged prep + hist (one dispatch):
//   blocks [0,4096)     : per-row histogram
//   blocks [4096,6144)  : W1 -> W1b bf16 conversion (div-free)
//   blocks [6144,6656)  : W2 -> W2T transpose
//   blocks [6656,8704)  : hid init (initHid only; S=1 gemm writes hid fully)
// ---------------------------------------------------------------------------
__global__ void k_preph(const int* __restrict__ words, bf16_t* __restrict__ hist,
                        const float* __restrict__ W1, bf16_t* __restrict__ W1b,
                        const float* __restrict__ W2, float* __restrict__ W2T,
                        const float* __restrict__ b1, float* __restrict__ hid,
                        int initHid) {
    __shared__ uint32_t h2[KPAD / 2];         // 20 KB (hist branch only)
    const int bid = blockIdx.x, tid = threadIdx.x;
    if (bid < BATCH) {
        hist_body(h2, words, hist, bid, bid, tid);
    } else if (bid < BATCH + 2048) {
        const int b2i = bid - BATCH;
        const int row = b2i >> 1;             // 0..1023
        const int g0  = (b2i & 1) * 1280;     // half-row of f32x4-groups
        for (int j = 0; j < 5; ++j) {
            int c4 = g0 + j * 256 + tid;
            bf16x4 o;
            if (c4 * 4 < CHARS) {
                f32x4 v = *(const f32x4*)(W1 + (size_t)row * CHARS + (size_t)c4 * 4);
                o[0] = (bf16_t)v[0]; o[1] = (bf16_t)v[1];
                o[2] = (bf16_t)v[2]; o[3] = (bf16_t)v[3];
            } else {
                o[0] = o[1] = o[2] = o[3] = (bf16_t)0.0f;
            }
            *(bf16x4*)(W1b + (size_t)row * KPAD + (size_t)c4 * 4) = o;
        }
    } else if (bid < BATCH + 2560) {
        int i = (bid - BATCH - 2048) * 256 + tid;
        int o = i & (OPAD - 1), k = i >> 7;
        W2T[i] = (o < OUTPUT) ? W2[(size_t)o * HIDDEN + k] : 0.0f;
    } else if (initHid) {
        const int b2i = bid - BATCH - 2560;
        const int M4 = BATCH * HIDDEN / 4;
        for (int i = b2i * 256 + tid; i < M4; i += 2048 * 256) {
            int h4 = i & (HIDDEN / 4 - 1);
            ((f32x4*)hid)[i] = ((const f32x4*)b1)[h4];
        }
    }
}

// ---------------------------------------------------------------------------
// R14: 128x128x(BK=64) bf16 MFMA GEMM, S=1, 2 blocks/CU.
//   Grid 32x8 = 256 blocks; LDS 64KB (2 blocks/CU -> 16 waves/CU: cross-block
//   TLP covers the per-tile vmcnt(0)+barrier drain -- the m97 mechanism our
//   1-block/CU 256^2 kernel lacked). Kills split-K: no slabs, no k_red,
//   WRITE 65.9 -> 16.8MB, b1 fused in epilogue. Rows stay 128B -> R7's
//   verified conflict-free swizzle unchanged (chunk = ((kk<<2)|hi) ^ (row&7),
//   staging inverse (lane&7)^(lane>>3)).
//   Per wave (8 = 4M x 2N): 32x64 output, acc[2][4] f32x4 = 32 regs.
//   Per K-tile/wave: 4 gload16 + 12 ds_read_b128 + 16 MFMA, free-flow,
//   one vmcnt(0)+barrier per tile.
//   WAR: stage buf^1 while reading buf -- buf^1 last read one body earlier,
//   done at its end-barrier. RAW: vmcnt(0) before barrier drains this body's
//   4 stages; next body reads them after the barrier. Tail clamps to tile 0.
// ---------------------------------------------------------------------------
__global__ void __launch_bounds__(512, 4)
k_gemm1(const bf16_t* __restrict__ A, const bf16_t* __restrict__ Bt,
        float* __restrict__ hid, const float* __restrict__ b1) {
    __shared__ __attribute__((aligned(16))) bf16_t As[2][128 * 64];  // 32 KB
    __shared__ __attribute__((aligned(16))) bf16_t Bs[2][128 * 64];  // 32 KB

    const int nblk = gridDim.x;           // 256
    int idx = blockIdx.x;
    idx = (idx & 7) * (nblk >> 3) + (idx >> 3);   // XCD chunk swizzle
    const int mt = idx & 31;              // 0..31
    const int nt = idx >> 5;              // 0..7
    const int m0 = mt * 128;
    const int n0 = nt * 128;

    const int tid  = threadIdx.x;
    const int lane = tid & 63;
    const int wave = tid >> 6;            // 0..7 = 4M x 2N
    const int wm32 = (wave >> 1) * 32;
    const int wn64 = (wave & 1) * 64;
    const int l15  = lane & 15;
    const int hi   = lane >> 4;
    const int x3   = l15 & 7;

    int arow[2], brow[4], koff[2];
#pragma unroll
    for (int fi = 0; fi < 2; ++fi) arow[fi] = (wm32 + fi * 16 + l15) * 128;
#pragma unroll
    for (int fj = 0; fj < 4; ++fj) brow[fj] = (wn64 + fj * 16 + l15) * 128;
#pragma unroll
    for (int kk = 0; kk < 2; ++kk) koff[kk] = ((((kk << 2) | hi)) ^ x3) * 16;

    // staging: wave covers 16 rows (2 issues x 8); lane -> row lane>>3,
    // chunk (lane&7)^(lane>>3) [inverse swizzle]
    const int srow = lane >> 3;
    const int csw8 = ((lane & 7) ^ srow) * 8;
    const bf16_t* Ab = A  + (size_t)(m0 + wave * 16 + srow) * KPAD + csw8;
    const bf16_t* Bb = Bt + (size_t)(n0 + wave * 16 + srow) * KPAD + csw8;
    const int wsl = wave * 1024;          // 16 rows x 64 elems

    f32x4 acc[2][4] = {};

#define STAGE4(BUF, KTILE_) do {                                               \
    int kte_ = (KTILE_); if (kte_ >= 160) kte_ = 0; /* tail clamp */           \
    const size_t kc_ = (size_t)kte_ * 64;                                      \
    gload16(Ab + kc_,                      &As[BUF][0] + wsl);                 \
    gload16(Ab + (size_t)8 * KPAD + kc_,   &As[BUF][0] + wsl + 512);           \
    gload16(Bb + kc_,                      &Bs[BUF][0] + wsl);                 \
    gload16(Bb + (size_t)8 * KPAD + kc_,   &Bs[BUF][0] + wsl + 512);           \
} while (0)

#define BODY(CUR, NXT, KTN) do {                                               \
    STAGE4(NXT, KTN);                                                          \
    bf16x8 af_[2][2], bf_[2][4];                                               \
    _Pragma("unroll") for (int kk = 0; kk < 2; ++kk) {                         \
        _Pragma("unroll") for (int fi = 0; fi < 2; ++fi)                       \
            af_[kk][fi] = *(const bf16x8*)((const char*)&As[CUR][0] +          \
                                           arow[fi] + koff[kk]);               \
        _Pragma("unroll") for (int fj = 0; fj < 4; ++fj)                       \
            bf_[kk][fj] = *(const bf16x8*)((const char*)&Bs[CUR][0] +          \
                                           brow[fj] + koff[kk]);               \
    }                                                                          \
    _Pragma("unroll") for (int kk = 0; kk < 2; ++kk)                           \
        _Pragma("unroll") for (int fi = 0; fi < 2; ++fi)                       \
            _Pragma("unroll") for (int fj = 0; fj < 4; ++fj)                   \
                acc[fi][fj] = __builtin_amdgcn_mfma_f32_16x16x32_bf16(         \
                    af_[kk][fi], bf_[kk][fj], acc[fi][fj], 0, 0, 0);           \
    asm volatile("s_waitcnt vmcnt(0)" ::: "memory");                           \
    __builtin_amdgcn_sched_barrier(0);                                         \
    __builtin_amdgcn_s_barrier();                                              \
    __builtin_amdgcn_sched_barrier(0);                                         \
} while (0)

    // prologue: tile0 -> buf0
    STAGE4(0, 0);
    asm volatile("s_waitcnt vmcnt(0)" ::: "memory");
    __builtin_amdgcn_s_barrier();
    __builtin_amdgcn_sched_barrier(0);

    for (int kt = 0; kt < 160; kt += 2) {
        BODY(0, 1, kt + 1);
        BODY(1, 0, kt + 2);
    }
#undef BODY
#undef STAGE4

    // epilogue: C/D col=lane&15, row=(lane>>4)*4+reg [guide §3, m89]; + b1
    const int er = hi * 4;
#pragma unroll
    for (int fi = 0; fi < 2; ++fi)
#pragma unroll
    for (int fj = 0; fj < 4; ++fj) {
        const int col = n0 + wn64 + fj * 16 + l15;
        const float bv = b1[col];
        float* dst = hid + (size_t)(m0 + wm32 + fi * 16 + er) * HIDDEN + col;
#pragma unroll
        for (int r = 0; r < 4; ++r)
            dst[(size_t)r * HIDDEN] = acc[fi][fj][r] + bv;
    }
}

// ---------------------------------------------------------------------------
// Legacy 256x256 8-phase GEMM with atomic epilogue (fallback paths only)
// ---------------------------------------------------------------------------
__global__ void __launch_bounds__(512)
k_gemm(const bf16_t* __restrict__ A, const bf16_t* __restrict__ Bt,
       float* __restrict__ hid, int KT, int mtiles) {
    __shared__ __attribute__((aligned(16))) bf16_t As[2][2][128 * 64];
    __shared__ __attribute__((aligned(16))) bf16_t Bs[2][2][128 * 64];

    const int nblk = gridDim.x;
    int idx = blockIdx.x;
    if ((nblk & 7) == 0) idx = (idx & 7) * (nblk >> 3) + (idx >> 3);
    const int mt = idx % mtiles;
    const int ns = idx / mtiles;
    const int m0 = mt * 256;
    const int n0 = (ns & 3) * 256;
    const int kbeg = (ns >> 2) * KT;

    const int tid  = threadIdx.x;
    const int lane = tid & 63;
    const int wave = tid >> 6;
    const int wm64 = (wave >> 2) * 64;
    const int wn32 = (wave & 3) * 32;
    const int l15  = lane & 15;
    const int hi   = lane >> 4;
    const int x3   = l15 & 7;

    int arow[4], brow[2], koff[2];
#pragma unroll
    for (int fi = 0; fi < 4; ++fi) arow[fi] = (wm64 + fi * 16 + l15) * 128;
#pragma unroll
    for (int fj = 0; fj < 2; ++fj) brow[fj] = (wn32 + fj * 16 + l15) * 128;
#pragma unroll
    for (int kk = 0; kk < 2; ++kk) koff[kk] = ((((kk << 2) | hi)) ^ x3) * 16;

    const int srow = lane >> 3;
    const int csw8 = ((lane & 7) ^ srow) * 8;
    const bf16_t* Ab = A  + (size_t)(m0 + wave * 16 + srow) * KPAD + csw8;
    const bf16_t* Bb = Bt + (size_t)(n0 + wave * 16 + srow) * KPAD + csw8;
    const int wsl = wave * 2 * 512;

    f32x4 acc[2][2][4][2] = {};
    bf16x8 Afa0[2][4], Afa1[2][4], Bfa0[2][4], Bfa1[2][4];
    bf16x8 Afb0[2][2], Afb1[2][2], Bfb0[2][2], Bfb1[2][2];

#define STAGE(SB, SOP, SH, KTILE_) do {                                        \
    int kte_ = (KTILE_); if (kte_ >= KT) kte_ = 0;                             \
    const size_t kc_ = (size_t)(kbeg + kte_) * 64;                             \
    const bf16_t* gb_ = (SOP) ? Bb : Ab;                                       \
    bf16_t* lb_ = ((SOP) ? &Bs[SB][SH][0] : &As[SB][SH][0]) + wsl;             \
    gload16(gb_ + (size_t)((SH) * 128)     * KPAD + kc_, lb_);                 \
    gload16(gb_ + (size_t)((SH) * 128 + 8) * KPAD + kc_, lb_ + 512);           \
} while (0)

#define LOADA(DST, PB, HALF) do {                                              \
    const char* p_ = (const char*)&As[PB][HALF][0];                            \
    _Pragma("unroll") for (int kk = 0; kk < 2; ++kk)                           \
        _Pragma("unroll") for (int fi = 0; fi < 4; ++fi)                       \
            DST[kk][fi] = *(const bf16x8*)(p_ + arow[fi] + koff[kk]);          \
} while (0)

#define LOADB(DST, PB, HALF) do {                                              \
    const char* p_ = (const char*)&Bs[PB][HALF][0];                            \
    _Pragma("unroll") for (int kk = 0; kk < 2; ++kk)                           \
        _Pragma("unroll") for (int fj = 0; fj < 2; ++fj)                       \
            DST[kk][fj] = *(const bf16x8*)(p_ + brow[fj] + koff[kk]);          \
} while (0)

#define PHB() do {                                                             \
    __builtin_amdgcn_sched_barrier(0);                                         \
    __builtin_amdgcn_s_barrier();                                              \
    __builtin_amdgcn_sched_barrier(0);                                         \
} while (0)

#define VM4() asm volatile("s_waitcnt vmcnt(4)" ::: "memory")

#define MMQ(QI, QJ, FA, FB) do {                                               \
    __builtin_amdgcn_s_setprio(1);                                             \
    _Pragma("unroll") for (int kk = 0; kk < 2; ++kk)                           \
        _Pragma("unroll") for (int fi = 0; fi < 4; ++fi)                       \
            _Pragma("unroll") for (int fj = 0; fj < 2; ++fj)                   \
                acc[QI][QJ][fi][fj] = __builtin_amdgcn_mfma_f32_16x16x32_bf16( \
                    FA[kk][fi], FB[kk][fj], acc[QI][QJ][fi][fj], 0, 0, 0);     \
    __builtin_amdgcn_s_setprio(0);                                             \
} while (0)

    STAGE(0, 0, 0, 0);
    STAGE(0, 1, 0, 0);
    STAGE(0, 0, 1, 0);
    STAGE(0, 1, 1, 0);
    STAGE(1, 1, 0, 1);
    STAGE(1, 0, 0, 1);
    VM4();
    PHB();
    LOADA(Afa0, 0, 0);
    LOADB(Afb0, 0, 0);

    for (int kt = 0; kt < KT; kt += 2) {
        PHB();
        STAGE(1, 0, 1, kt + 1);
        LOADA(Afa1, 0, 1);
        MMQ(0, 0, Afa0, Afb0);
        VM4();
        PHB();
        STAGE(1, 1, 1, kt + 1);
        LOADB(Afb1, 0, 1);
        MMQ(1, 0, Afa1, Afb0);
        PHB();
        STAGE(0, 1, 0, kt + 2);
        MMQ(0, 1, Afa0, Afb1);
        VM4();
        PHB();
        STAGE(0, 0, 0, kt + 2);
        LOADA(Bfa0, 1, 0);
        LOADB(Bfb0, 1, 0);
        MMQ(1, 1, Afa1, Afb1);
        PHB();
        STAGE(0, 0, 1, kt + 2);
        LOADA(Bfa1, 1, 1);
        MMQ(0, 0, Bfa0, Bfb0);
        VM4();
        PHB();
        STAGE(0, 1, 1, kt + 2);
        LOADB(Bfb1, 1, 1);
        MMQ(1, 0, Bfa1, Bfb0);
        PHB();
        STAGE(1, 1, 0, kt + 3);
        MMQ(0, 1, Bfa0, Bfb1);
        VM4();
        PHB();
        STAGE(1, 0, 0, kt + 3);
        LOADA(Afa0, 0, 0);
        LOADB(Afb0, 0, 0);
        MMQ(1, 1, Bfa1, Bfb1);
    }
#undef MMQ
#undef VM4
#undef PHB
#undef LOADB
#undef LOADA
#undef STAGE

    const int er = hi * 4;
#pragma unroll
    for (int qi = 0; qi < 2; ++qi)
#pragma unroll
    for (int qj = 0; qj < 2; ++qj)
#pragma unroll
    for (int fi = 0; fi < 4; ++fi)
#pragma unroll
    for (int fj = 0; fj < 2; ++fj) {
        float* dst = hid + (size_t)(m0 + qi * 128 + wm64 + fi * 16 + er) * HIDDEN
                         + (n0 + qj * 128 + wn32 + fj * 16 + l15);
#pragma unroll
        for (int r = 0; r < 4; ++r)
            atomicAdd(dst + (size_t)r * HIDDEN, acc[qi][qj][fi][fj][r]);
    }
}

// ---------------------------------------------------------------------------
// Output GEMV v2 -- register-blocked rows (R12, verified: W2T L2 traffic /8)
// ---------------------------------------------------------------------------
__global__ void k_out2(const float* __restrict__ hid, const float* __restrict__ W2T,
                       const float* __restrict__ b2, float* __restrict__ out) {
    __shared__ float red[4][16][OPAD];    // 32 KB: [kc][row][o]
    const int tid  = threadIdx.x;
    const int o4   = (tid & 31) * 4;      // 0..124
    const int slot = tid >> 5;            // 0..7
    const int rg   = slot >> 2;           // 0..1  (row-group of 8)
    const int kc   = slot & 3;            // k-chunk [kc*256, +256)
    const int rbase = blockIdx.x * 16 + rg * 8;

    f32x4 acc8[8] = {};
    const int k0beg = kc * 256;
    for (int k0 = k0beg; k0 < k0beg + 256; k0 += 4) {
        f32x4 wv0 = *(const f32x4*)(W2T + (size_t)(k0 + 0) * OPAD + o4);
        f32x4 wv1 = *(const f32x4*)(W2T + (size_t)(k0 + 1) * OPAD + o4);
        f32x4 wv2 = *(const f32x4*)(W2T + (size_t)(k0 + 2) * OPAD + o4);
        f32x4 wv3 = *(const f32x4*)(W2T + (size_t)(k0 + 3) * OPAD + o4);
#pragma unroll
        for (int r = 0; r < 8; ++r) {
            f32x4 hv = *(const f32x4*)(hid + (size_t)(rbase + r) * HIDDEN + k0);
            acc8[r] += hv[0] * wv0 + hv[1] * wv1 + hv[2] * wv2 + hv[3] * wv3;
        }
    }
#pragma unroll
    for (int r = 0; r < 8; ++r)
        *(f32x4*)&red[kc][rg * 8 + r][o4] = acc8[r];
    __syncthreads();
    const int row = tid >> 4;             // 0..15
    const int o8  = (tid & 15) * 8;       // 0..120
    f32x4 s0 = {0.f, 0.f, 0.f, 0.f}, s1 = {0.f, 0.f, 0.f, 0.f};
#pragma unroll
    for (int c = 0; c < 4; ++c) {
        s0 += *(const f32x4*)&red[c][row][o8];
        s1 += *(const f32x4*)&red[c][row][o8 + 4];
    }
    float* op = out + (size_t)(blockIdx.x * 16 + row) * OUTPUT;
#pragma unroll
    for (int j = 0; j < 4; ++j) {
        if (o8 + j < OUTPUT)     op[o8 + j]     = s0[j] + b2[o8 + j];
        if (o8 + 4 + j < OUTPUT) op[o8 + 4 + j] = s1[j] + b2[o8 + 4 + j];
    }
}

// ---------------------------------------------------------------------------
// Lean output GEMV (fallback paths; hid already complete incl. b1)
// ---------------------------------------------------------------------------
__global__ void k_out(const float* __restrict__ hid, const float* __restrict__ W2T,
                      const float* __restrict__ b2, float* __restrict__ out) {
    const int tid = threadIdx.x;
    const int o4  = (tid & 31) * 4;
    const int rs  = tid >> 5;
    const int row = blockIdx.x * 8 + rs;
    const float* hrow = hid + (size_t)row * HIDDEN;
    f32x4 acc = {0.f, 0.f, 0.f, 0.f};
    for (int k0 = 0; k0 < HIDDEN; k0 += 4) {
        f32x4 hv = *(const f32x4*)(hrow + k0);
#pragma unroll
        for (int q = 0; q < 4; ++q) {
            f32x4 wv = *(const f32x4*)(W2T + (size_t)(k0 + q) * OPAD + o4);
            acc += hv[q] * wv;
        }
    }
    if (o4 < OUTPUT) {
        float* op = out + (size_t)row * OUTPUT + o4;
#pragma unroll
        for (int q = 0; q < 4; ++q)
            op[q] = acc[q] + b2[o4 + q];
    }
}

// ---------------------------------------------------------------------------
static inline int pick_S(int mtiles) {
    const int cands[10] = {80, 40, 20, 16, 10, 8, 5, 4, 2, 1};
    for (int i = 0; i < 10; ++i)
        if (mtiles * 4 * cands[i] <= 256) return cands[i];
    return 1;
}

extern "C" void kernel_launch(void* const* d_in, const int* in_sizes, int n_in,
                              void* d_out, int out_size, void* d_ws, size_t ws_size,
                              hipStream_t stream) {
    (void)in_sizes; (void)n_in; (void)out_size;
    const int*   words = (const int*)d_in[0];
    const float* W1    = (const float*)d_in[1];
    const float* b1    = (const float*)d_in[2];
    const float* W2    = (const float*)d_in[3];
    const float* b2    = (const float*)d_in[4];
    float* out = (float*)d_out;

    // workspace layout
    char* ws = (char*)d_ws;
    size_t off = 0;
    bf16_t* W1b  = (bf16_t*)(ws + off); off += (size_t)HIDDEN * KPAD * sizeof(bf16_t); // 21.0 MB
    float*  hid  = (float*) (ws + off); off += (size_t)BATCH * HIDDEN * sizeof(float); // 16.8 MB
    float*  W2T  = (float*) (ws + off); off += (size_t)HIDDEN * OPAD * sizeof(float);  // 0.5 MB
    const size_t histBytes = (size_t)BATCH * KPAD * sizeof(bf16_t);                    // 83.9 MB

    if (ws_size >= off + histBytes) {
        // fast path: 3 dispatches -- prep+hist, S=1 gemm (b1 fused), GEMV
        bf16_t* histC = (bf16_t*)(ws + off);
        k_preph<<<dim3(BATCH + 4608), dim3(256), 0, stream>>>(
            words, histC, W1, W1b, W2, W2T, b1, hid, 0);
        k_gemm1<<<dim3(256), dim3(512), 0, stream>>>(histC, W1b, hid, b1);
        k_out2<<<dim3(BATCH / 16), dim3(256), 0, stream>>>(hid, W2T, b2, out);
    } else {
        // chunked fallback (small workspace)
        bf16_t* histC = (bf16_t*)(ws + off);
        size_t rem = (ws_size > off) ? (ws_size - off) : 0;
        int chunkRows = (int)(rem / ((size_t)KPAD * sizeof(bf16_t)));
        chunkRows = (chunkRows / 256) * 256;
        if (chunkRows > BATCH) chunkRows = BATCH;
        if (chunkRows < 256)   chunkRows = 256;

        k_prep<<<dim3(4608), dim3(256), 0, stream>>>(W1, W1b, W2, W2T, b1, hid);
        for (int r0 = 0; r0 < BATCH; r0 += chunkRows) {
            int rows = BATCH - r0;
            if (rows > chunkRows) rows = chunkRows;
            k_hist<<<dim3(rows), dim3(256), 0, stream>>>(words, histC, r0);
            int mtiles = rows / 256;
            int S = pick_S(mtiles);
            int KT = (KPAD / 64) / S;
            k_gemm<<<dim3(mtiles * 4 * S), dim3(512), 0, stream>>>(
                histC, W1b, hid + (size_t)r0 * HIDDEN, KT, mtiles);
        }
        k_out<<<dim3(BATCH / 8), dim3(256), 0, stream>>>(hid, W2T, b2, out);
    }
}

// Round 16
// 254.666 us; speedup vs baseline: 1.2999x; 1.2999x over previous
//
#include <hip/hip_runtime.h>
#include <stdint.h>

// Problem constants (fixed by the reference)
#define CHARS   10000
#define KPAD    10240   // K padded to multiple of 64
#define HIDDEN  1024
#define OUTPUT  100
#define OPAD    128     // padded output cols for coalesced W2T
#define BATCH   4096
#define MAXLEN  2048

typedef __bf16 bf16_t;
typedef __bf16 bf16x8 __attribute__((ext_vector_type(8)));
typedef __bf16 bf16x4 __attribute__((ext_vector_type(4)));
typedef float  f32x4  __attribute__((ext_vector_type(4)));
typedef uint32_t u32x4 __attribute__((ext_vector_type(4)));

// async global->LDS, 16B per lane; LDS dst = wave-uniform base + lane*16 (linear)
__device__ __forceinline__ void gload16(const bf16_t* g, bf16_t* l) {
    __builtin_amdgcn_global_load_lds(
        (__attribute__((address_space(1))) void*)const_cast<bf16_t*>(g),
        (__attribute__((address_space(3))) void*)l, 16, 0, 0);
}

// ---------------------------------------------------------------------------
// Legacy split prep (used only on the chunked fallback path)
// ---------------------------------------------------------------------------
__global__ void k_prep(const float* __restrict__ W1, bf16_t* __restrict__ W1b,
                       const float* __restrict__ W2, float* __restrict__ W2T,
                       const float* __restrict__ b1, float* __restrict__ hid) {
    const int bid = blockIdx.x, tid = threadIdx.x;
    if (bid < 2048) {
        const int row = bid >> 1;
        const int g0  = (bid & 1) * 1280;
        for (int j = 0; j < 5; ++j) {
            int c4 = g0 + j * 256 + tid;
            bf16x4 o;
            if (c4 * 4 < CHARS) {
                f32x4 v = *(const f32x4*)(W1 + (size_t)row * CHARS + (size_t)c4 * 4);
                o[0] = (bf16_t)v[0]; o[1] = (bf16_t)v[1];
                o[2] = (bf16_t)v[2]; o[3] = (bf16_t)v[3];
            } else {
                o[0] = o[1] = o[2] = o[3] = (bf16_t)0.0f;
            }
            *(bf16x4*)(W1b + (size_t)row * KPAD + (size_t)c4 * 4) = o;
        }
    } else if (bid < 2560) {
        int i = (bid - 2048) * 256 + tid;
        int o = i & (OPAD - 1), k = i >> 7;
        W2T[i] = (o < OUTPUT) ? W2[(size_t)o * HIDDEN + k] : 0.0f;
    } else {
        const int M4 = BATCH * HIDDEN / 4;
        for (int i = (bid - 2560) * 256 + tid; i < M4; i += 2048 * 256) {
            int h4 = i & (HIDDEN / 4 - 1);
            ((f32x4*)hid)[i] = ((const f32x4*)b1)[h4];
        }
    }
}

// ---------------------------------------------------------------------------
// Per-row histogram body, u16-packed (R13; counts < 2^11 per half, no carry)
// ---------------------------------------------------------------------------
__device__ __forceinline__ void hist_body(uint32_t* h2, const int* __restrict__ words,
                                          bf16_t* __restrict__ hist, int row,
                                          int dstRow, int tid) {
#pragma unroll
    for (int i = 0; i < KPAD / 2 / 4 / 256; ++i)  // 5 iters
        *(u32x4*)(h2 + (i * 256 + tid) * 4) = (u32x4){0u, 0u, 0u, 0u};
    __syncthreads();
    const int* w = words + (size_t)row * MAXLEN;
#pragma unroll
    for (int i = 0; i < MAXLEN / 4 / 256; ++i) {  // 2 iters
        int4 t4 = *(const int4*)(w + (i * 256 + tid) * 4);
        atomicAdd(&h2[t4.x >> 1], 1u << ((t4.x & 1) * 16));
        atomicAdd(&h2[t4.y >> 1], 1u << ((t4.y & 1) * 16));
        atomicAdd(&h2[t4.z >> 1], 1u << ((t4.z & 1) * 16));
        atomicAdd(&h2[t4.w >> 1], 1u << ((t4.w & 1) * 16));
    }
    __syncthreads();
    bf16_t* dst = hist + (size_t)dstRow * KPAD;
#pragma unroll
    for (int i = 0; i < KPAD / 8 / 256; ++i) {    // 5 iters
        int j = (i * 256 + tid) * 8;              // j/2 is 4-aligned -> 16B ok
        u32x4 v = *(const u32x4*)(h2 + (j >> 1));
        bf16x8 o;
#pragma unroll
        for (int q = 0; q < 4; ++q) {
            o[2 * q]     = (bf16_t)(float)(v[q] & 0xffffu);
            o[2 * q + 1] = (bf16_t)(float)(v[q] >> 16);
        }
        *(bf16x8*)(dst + j) = o;
    }
}

__global__ void k_hist(const int* __restrict__ words, bf16_t* __restrict__ hist,
                       int rowStart) {
    __shared__ uint32_t h2[KPAD / 2];         // 20 KB
    hist_body(h2, words, hist, rowStart + blockIdx.x, blockIdx.x, threadIdx.x);
}

// ---------------------------------------------------------------------------
// Merged prep + hist (one dispatch)
// ---------------------------------------------------------------------------
__global__ void k_preph(const int* __restrict__ words, bf16_t* __restrict__ hist,
                        const float* __restrict__ W1, bf16_t* __restrict__ W1b,
                        const float* __restrict__ W2, float* __restrict__ W2T,
                        const float* __restrict__ b1, float* __restrict__ hid,
                        int initHid) {
    __shared__ uint32_t h2[KPAD / 2];         // 20 KB (hist branch only)
    const int bid = blockIdx.x, tid = threadIdx.x;
    if (bid < BATCH) {
        hist_body(h2, words, hist, bid, bid, tid);
    } else if (bid < BATCH + 2048) {
        const int b2i = bid - BATCH;
        const int row = b2i >> 1;             // 0..1023
        const int g0  = (b2i & 1) * 1280;     // half-row of f32x4-groups
        for (int j = 0; j < 5; ++j) {
            int c4 = g0 + j * 256 + tid;
            bf16x4 o;
            if (c4 * 4 < CHARS) {
                f32x4 v = *(const f32x4*)(W1 + (size_t)row * CHARS + (size_t)c4 * 4);
                o[0] = (bf16_t)v[0]; o[1] = (bf16_t)v[1];
                o[2] = (bf16_t)v[2]; o[3] = (bf16_t)v[3];
            } else {
                o[0] = o[1] = o[2] = o[3] = (bf16_t)0.0f;
            }
            *(bf16x4*)(W1b + (size_t)row * KPAD + (size_t)c4 * 4) = o;
        }
    } else if (bid < BATCH + 2560) {
        int i = (bid - BATCH - 2048) * 256 + tid;
        int o = i & (OPAD - 1), k = i >> 7;
        W2T[i] = (o < OUTPUT) ? W2[(size_t)o * HIDDEN + k] : 0.0f;
    } else if (initHid) {
        const int b2i = bid - BATCH - 2560;
        const int M4 = BATCH * HIDDEN / 4;
        for (int i = b2i * 256 + tid; i < M4; i += 2048 * 256) {
            int h4 = i & (HIDDEN / 4 - 1);
            ((f32x4*)hid)[i] = ((const f32x4*)b1)[h4];
        }
    }
}

// ---------------------------------------------------------------------------
// 256x256x(BK=64) bf16 MFMA GEMM, 8-phase schedule.
//   R16 = R15's m201 issue order with the CROSS-WAVE ledger fixed.
//   R15's bug: vmcnt is per-wave; a stage is cross-wave-visible only at a
//   barrier where EVERY wave already passed a waitcnt covering it. R15's
//   sparse VM4s left st6prev/st8prev/st2/st4 unconfirmed at the barriers
//   preceding their readers (4 races), and the prologue barrier was missing
//   entirely -> absmax 0.227.
//   Fix (uniform, derived): every read issued at phase p+1 touches a region
//   staged exactly 4 stages earlier -> every phase's barrier must confirm
//   "all but the 3 newest stages" -> vmcnt(6) (3 stages x 2 loads) before
//   EVERY s_barrier; lgkmcnt(0) after it; prologue = vmcnt(4) + s_barrier.
//   Each stage gets 3 phases (~600+ cy) to land before its vmcnt deadline.
//   Phase p: {STAGE; issue reads for phase p+1} -> vmcnt(6) -> barrier ->
//   lgkmcnt(0) -> MFMA(frags read at p-1): all 8 waves' reads overlap the
//   rendezvous skew, so the post-barrier wait is ~free.
//   EPI=1: split-K slices store to private slabs (k_red sums). EPI=0: atomic.
// ---------------------------------------------------------------------------
template <int EPI>
__global__ void __launch_bounds__(512)
k_gemm(const bf16_t* __restrict__ A, const bf16_t* __restrict__ Bt,
       float* __restrict__ hid, float* __restrict__ extraSlabs,
       int KT, int mtiles) {
    __shared__ __attribute__((aligned(16))) bf16_t As[2][2][128 * 64];  // 64 KB
    __shared__ __attribute__((aligned(16))) bf16_t Bs[2][2][128 * 64];  // 64 KB

    const int nblk = gridDim.x;
    int idx = blockIdx.x;
    if ((nblk & 7) == 0) idx = (idx & 7) * (nblk >> 3) + (idx >> 3);
    const int mt = idx % mtiles;
    const int ns = idx / mtiles;
    const int m0 = mt * 256;
    const int n0 = (ns & 3) * 256;        // HIDDEN/256 == 4
    const int kbeg = (ns >> 2) * KT;      // k-slice start, in 64-wide tiles

    const int tid  = threadIdx.x;
    const int lane = tid & 63;
    const int wave = tid >> 6;            // 0..7
    const int wm64 = (wave >> 2) * 64;
    const int wn32 = (wave & 3) * 32;
    const int l15  = lane & 15;
    const int hi   = lane >> 4;
    const int x3   = l15 & 7;

    int arow[4], brow[2], koff[2];
#pragma unroll
    for (int fi = 0; fi < 4; ++fi) arow[fi] = (wm64 + fi * 16 + l15) * 128;
#pragma unroll
    for (int fj = 0; fj < 2; ++fj) brow[fj] = (wn32 + fj * 16 + l15) * 128;
#pragma unroll
    for (int kk = 0; kk < 2; ++kk) koff[kk] = ((((kk << 2) | hi)) ^ x3) * 16;

    const int srow = lane >> 3;
    const int csw8 = ((lane & 7) ^ srow) * 8;
    const bf16_t* Ab = A  + (size_t)(m0 + wave * 16 + srow) * KPAD + csw8;
    const bf16_t* Bb = Bt + (size_t)(n0 + wave * 16 + srow) * KPAD + csw8;
    const int wsl = wave * 2 * 512;

    f32x4 acc[2][2][4][2] = {};
    bf16x8 Afa0[2][4], Afa1[2][4], Bfa0[2][4], Bfa1[2][4];
    bf16x8 Afb0[2][2], Afb1[2][2], Bfb0[2][2], Bfb1[2][2];

#define STAGE(SB, SOP, SH, KTILE_) do {                                        \
    int kte_ = (KTILE_); if (kte_ >= KT) kte_ = 0; /* tail clamp */            \
    const size_t kc_ = (size_t)(kbeg + kte_) * 64;                             \
    const bf16_t* gb_ = (SOP) ? Bb : Ab;                                       \
    bf16_t* lb_ = ((SOP) ? &Bs[SB][SH][0] : &As[SB][SH][0]) + wsl;             \
    gload16(gb_ + (size_t)((SH) * 128)     * KPAD + kc_, lb_);                 \
    gload16(gb_ + (size_t)((SH) * 128 + 8) * KPAD + kc_, lb_ + 512);           \
} while (0)

#define LOADA(DST, PB, HALF) do {                                              \
    const char* p_ = (const char*)&As[PB][HALF][0];                            \
    _Pragma("unroll") for (int kk = 0; kk < 2; ++kk)                           \
        _Pragma("unroll") for (int fi = 0; fi < 4; ++fi)                       \
            DST[kk][fi] = *(const bf16x8*)(p_ + arow[fi] + koff[kk]);          \
} while (0)

#define LOADB(DST, PB, HALF) do {                                              \
    const char* p_ = (const char*)&Bs[PB][HALF][0];                            \
    _Pragma("unroll") for (int kk = 0; kk < 2; ++kk)                           \
        _Pragma("unroll") for (int fj = 0; fj < 2; ++fj)                       \
            DST[kk][fj] = *(const bf16x8*)(p_ + brow[fj] + koff[kk]);          \
} while (0)

// rendezvous: vmcnt(6) (all but 3 newest stages cross-wave-confirmable) ->
// barrier -> lgkmcnt(0) (reads issued pre-barrier by ALL waves overlapped
// the rendezvous skew) -> MFMA pinned below (rule 18).
#define PHW() do {                                                             \
    __builtin_amdgcn_sched_barrier(0);                                         \
    asm volatile("s_waitcnt vmcnt(6)" ::: "memory");                           \
    __builtin_amdgcn_s_barrier();                                              \
    __builtin_amdgcn_sched_barrier(0);                                         \
    asm volatile("s_waitcnt lgkmcnt(0)" ::: "memory");                         \
    __builtin_amdgcn_sched_barrier(0);                                         \
} while (0)

#define MMQ(QI, QJ, FA, FB) do {                                               \
    __builtin_amdgcn_s_setprio(1);                                             \
    _Pragma("unroll") for (int kk = 0; kk < 2; ++kk)                           \
        _Pragma("unroll") for (int fi = 0; fi < 4; ++fi)                       \
            _Pragma("unroll") for (int fj = 0; fj < 2; ++fj)                   \
                acc[QI][QJ][fi][fj] = __builtin_amdgcn_mfma_f32_16x16x32_bf16( \
                    FA[kk][fi], FB[kk][fj], acc[QI][QJ][fi][fj], 0, 0, 0);     \
    __builtin_amdgcn_s_setprio(0);                                             \
} while (0)

    // prologue: tile0 -> buf0 (stages 1-4), tile1 {B0,A0} -> buf1 (5,6).
    // vmcnt(4) confirms the 4 buf0 stages; barrier makes them cross-wave
    // visible; then issue ph1's reads (b0A0,b0B0).
    STAGE(0, 0, 0, 0);
    STAGE(0, 1, 0, 0);
    STAGE(0, 0, 1, 0);
    STAGE(0, 1, 1, 0);
    STAGE(1, 1, 0, 1);
    STAGE(1, 0, 0, 1);
    asm volatile("s_waitcnt vmcnt(4)" ::: "memory");
    __builtin_amdgcn_s_barrier();
    __builtin_amdgcn_sched_barrier(0);
    LOADA(Afa0, 0, 0);
    LOADB(Afb0, 0, 0);

    for (int kt = 0; kt < KT; kt += 2) {
        // ph1: stage b1A1(t+1) [st1], read b0A1 (st5prev/prologue-st3)
        STAGE(1, 0, 1, kt + 1);
        LOADA(Afa1, 0, 1);
        PHW();
        MMQ(0, 0, Afa0, Afb0);
        // ph2: stage b1B1(t+1) [st2], read b0B1 (st6prev/prologue-st4)
        STAGE(1, 1, 1, kt + 1);
        LOADB(Afb1, 0, 1);
        PHW();
        MMQ(1, 0, Afa1, Afb0);
        // ph3: stage b0B0(t+2) [st3]
        STAGE(0, 1, 0, kt + 2);
        PHW();
        MMQ(0, 1, Afa0, Afb1);
        // ph4: stage b0A0(t+2) [st4], read b1A0,b1B0 (st8prev,st7prev/prol-5,6)
        STAGE(0, 0, 0, kt + 2);
        LOADA(Bfa0, 1, 0);
        LOADB(Bfb0, 1, 0);
        PHW();
        MMQ(1, 1, Afa1, Afb1);
        // ph5: stage b0A1(t+2) [st5], read b1A1 (st1)
        STAGE(0, 0, 1, kt + 2);
        LOADA(Bfa1, 1, 1);
        PHW();
        MMQ(0, 0, Bfa0, Bfb0);
        // ph6: stage b0B1(t+2) [st6], read b1B1 (st2)
        STAGE(0, 1, 1, kt + 2);
        LOADB(Bfb1, 1, 1);
        PHW();
        MMQ(1, 0, Bfa1, Bfb0);
        // ph7: stage b1B0(t+3) [st7]
        STAGE(1, 1, 0, kt + 3);
        PHW();
        MMQ(0, 1, Bfa0, Bfb1);
        // ph8: stage b1A0(t+3) [st8], read b0A0,b0B0 (st4,st3; dead last iter)
        STAGE(1, 0, 0, kt + 3);
        LOADA(Afa0, 0, 0);
        LOADB(Afb0, 0, 0);
        PHW();
        MMQ(1, 1, Bfa1, Bfb1);
    }
#undef MMQ
#undef PHW
#undef LOADB
#undef LOADA
#undef STAGE

    // epilogue: C/D layout col=lane&15, row=(lane>>4)*4+reg  [guide §3, m89]
    const int er = hi * 4;
    float* dstBase;
    if (EPI == 1) {
        const int s = ns >> 2;
        dstBase = (s == 0) ? hid : extraSlabs + (size_t)(s - 1) * BATCH * HIDDEN;
    } else {
        dstBase = hid;
    }
#pragma unroll
    for (int qi = 0; qi < 2; ++qi)
#pragma unroll
    for (int qj = 0; qj < 2; ++qj)
#pragma unroll
    for (int fi = 0; fi < 4; ++fi)
#pragma unroll
    for (int fj = 0; fj < 2; ++fj) {
        float* dst = dstBase + (size_t)(m0 + qi * 128 + wm64 + fi * 16 + er) * HIDDEN
                             + (n0 + qj * 128 + wn32 + fj * 16 + l15);
#pragma unroll
        for (int r = 0; r < 4; ++r) {
            if (EPI == 1) dst[(size_t)r * HIDDEN] = acc[qi][qj][fi][fj][r];
            else          atomicAdd(dst + (size_t)r * HIDDEN, acc[qi][qj][fi][fj][r]);
        }
    }
}

// ---------------------------------------------------------------------------
// hid = b1 + slab0(hid) + slab1 + slab2 + slab3   (in-place on slab0)
// ---------------------------------------------------------------------------
__global__ void k_red(float* __restrict__ hid, const float* __restrict__ extra,
                      const float* __restrict__ b1) {
    const int N4 = BATCH * HIDDEN / 4;
    const float* e0 = extra;
    const float* e1 = extra + (size_t)BATCH * HIDDEN;
    const float* e2 = extra + (size_t)2 * BATCH * HIDDEN;
    for (int i = blockIdx.x * 256 + threadIdx.x; i < N4; i += 2048 * 256) {
        int h4 = i & (HIDDEN / 4 - 1);
        f32x4 v = ((const f32x4*)hid)[i];
        v += ((const f32x4*)b1)[h4];
        v += ((const f32x4*)e0)[i];
        v += ((const f32x4*)e1)[i];
        v += ((const f32x4*)e2)[i];
        ((f32x4*)hid)[i] = v;
    }
}

// ---------------------------------------------------------------------------
// Output GEMV v2 -- register-blocked rows (R12, verified: W2T L2 traffic /8)
// ---------------------------------------------------------------------------
__global__ void k_out2(const float* __restrict__ hid, const float* __restrict__ W2T,
                       const float* __restrict__ b2, float* __restrict__ out) {
    __shared__ float red[4][16][OPAD];    // 32 KB: [kc][row][o]
    const int tid  = threadIdx.x;
    const int o4   = (tid & 31) * 4;      // 0..124
    const int slot = tid >> 5;            // 0..7
    const int rg   = slot >> 2;           // 0..1  (row-group of 8)
    const int kc   = slot & 3;            // k-chunk [kc*256, +256)
    const int rbase = blockIdx.x * 16 + rg * 8;

    f32x4 acc8[8] = {};
    const int k0beg = kc * 256;
    for (int k0 = k0beg; k0 < k0beg + 256; k0 += 4) {
        f32x4 wv0 = *(const f32x4*)(W2T + (size_t)(k0 + 0) * OPAD + o4);
        f32x4 wv1 = *(const f32x4*)(W2T + (size_t)(k0 + 1) * OPAD + o4);
        f32x4 wv2 = *(const f32x4*)(W2T + (size_t)(k0 + 2) * OPAD + o4);
        f32x4 wv3 = *(const f32x4*)(W2T + (size_t)(k0 + 3) * OPAD + o4);
#pragma unroll
        for (int r = 0; r < 8; ++r) {
            f32x4 hv = *(const f32x4*)(hid + (size_t)(rbase + r) * HIDDEN + k0);
            acc8[r] += hv[0] * wv0 + hv[1] * wv1 + hv[2] * wv2 + hv[3] * wv3;
        }
    }
#pragma unroll
    for (int r = 0; r < 8; ++r)
        *(f32x4*)&red[kc][rg * 8 + r][o4] = acc8[r];
    __syncthreads();
    const int row = tid >> 4;             // 0..15
    const int o8  = (tid & 15) * 8;       // 0..120
    f32x4 s0 = {0.f, 0.f, 0.f, 0.f}, s1 = {0.f, 0.f, 0.f, 0.f};
#pragma unroll
    for (int c = 0; c < 4; ++c) {
        s0 += *(const f32x4*)&red[c][row][o8];
        s1 += *(const f32x4*)&red[c][row][o8 + 4];
    }
    float* op = out + (size_t)(blockIdx.x * 16 + row) * OUTPUT;
#pragma unroll
    for (int j = 0; j < 4; ++j) {
        if (o8 + j < OUTPUT)     op[o8 + j]     = s0[j] + b2[o8 + j];
        if (o8 + 4 + j < OUTPUT) op[o8 + 4 + j] = s1[j] + b2[o8 + 4 + j];
    }
}

// ---------------------------------------------------------------------------
// Lean output GEMV (fallback paths; hid already complete incl. b1)
// ---------------------------------------------------------------------------
__global__ void k_out(const float* __restrict__ hid, const float* __restrict__ W2T,
                      const float* __restrict__ b2, float* __restrict__ out) {
    const int tid = threadIdx.x;
    const int o4  = (tid & 31) * 4;
    const int rs  = tid >> 5;
    const int row = blockIdx.x * 8 + rs;
    const float* hrow = hid + (size_t)row * HIDDEN;
    f32x4 acc = {0.f, 0.f, 0.f, 0.f};
    for (int k0 = 0; k0 < HIDDEN; k0 += 4) {
        f32x4 hv = *(const f32x4*)(hrow + k0);
#pragma unroll
        for (int q = 0; q < 4; ++q) {
            f32x4 wv = *(const f32x4*)(W2T + (size_t)(k0 + q) * OPAD + o4);
            acc += hv[q] * wv;
        }
    }
    if (o4 < OUTPUT) {
        float* op = out + (size_t)row * OUTPUT + o4;
#pragma unroll
        for (int q = 0; q < 4; ++q)
            op[q] = acc[q] + b2[o4 + q];
    }
}

// ---------------------------------------------------------------------------
static inline int pick_S(int mtiles) {
    const int cands[10] = {80, 40, 20, 16, 10, 8, 5, 4, 2, 1};
    for (int i = 0; i < 10; ++i)
        if (mtiles * 4 * cands[i] <= 256) return cands[i];
    return 1;
}

extern "C" void kernel_launch(void* const* d_in, const int* in_sizes, int n_in,
                              void* d_out, int out_size, void* d_ws, size_t ws_size,
                              hipStream_t stream) {
    (void)in_sizes; (void)n_in; (void)out_size;
    const int*   words = (const int*)d_in[0];
    const float* W1    = (const float*)d_in[1];
    const float* b1    = (const float*)d_in[2];
    const float* W2    = (const float*)d_in[3];
    const float* b2    = (const float*)d_in[4];
    float* out = (float*)d_out;

    // workspace layout
    char* ws = (char*)d_ws;
    size_t off = 0;
    bf16_t* W1b  = (bf16_t*)(ws + off); off += (size_t)HIDDEN * KPAD * sizeof(bf16_t); // 21.0 MB
    float*  hid  = (float*) (ws + off); off += (size_t)BATCH * HIDDEN * sizeof(float); // 16.8 MB
    float*  W2T  = (float*) (ws + off); off += (size_t)HIDDEN * OPAD * sizeof(float);  // 0.5 MB
    const size_t slabBytes = (size_t)BATCH * HIDDEN * sizeof(float);                   // 16.8 MB
    const size_t histBytes = (size_t)BATCH * KPAD * sizeof(bf16_t);                    // 83.9 MB

    if (ws_size >= off + 3 * slabBytes + histBytes) {
        // slab path: store-based split-K + streaming reduce + reg-blocked GEMV
        float* extra = (float*)(ws + off);
        bf16_t* histC = (bf16_t*)(ws + off + 3 * slabBytes);
        k_preph<<<dim3(BATCH + 4608), dim3(256), 0, stream>>>(
            words, histC, W1, W1b, W2, W2T, b1, hid, 0);
        int mtiles = BATCH / 256;                 // 16
        int S = 4;
        int KT = (KPAD / 64) / S;                 // 40
        k_gemm<1><<<dim3(mtiles * 4 * S), dim3(512), 0, stream>>>(
            histC, W1b, hid, extra, KT, mtiles);
        k_red<<<dim3(2048), dim3(256), 0, stream>>>(hid, extra, b1);
        k_out2<<<dim3(BATCH / 16), dim3(256), 0, stream>>>(hid, W2T, b2, out);
    } else {
        bf16_t* histC = (bf16_t*)(ws + off);
        size_t rem = (ws_size > off) ? (ws_size - off) : 0;
        int chunkRows = (int)(rem / ((size_t)KPAD * sizeof(bf16_t)));
        chunkRows = (chunkRows / 256) * 256;
        if (chunkRows > BATCH) chunkRows = BATCH;
        if (chunkRows < 256)   chunkRows = 256;

        if (chunkRows >= BATCH) {
            k_preph<<<dim3(BATCH + 4608), dim3(256), 0, stream>>>(
                words, histC, W1, W1b, W2, W2T, b1, hid, 1);
            int mtiles = BATCH / 256;
            int S = pick_S(mtiles);
            int KT = (KPAD / 64) / S;
            k_gemm<0><<<dim3(mtiles * 4 * S), dim3(512), 0, stream>>>(
                histC, W1b, hid, nullptr, KT, mtiles);
        } else {
            k_prep<<<dim3(4608), dim3(256), 0, stream>>>(W1, W1b, W2, W2T, b1, hid);
            for (int r0 = 0; r0 < BATCH; r0 += chunkRows) {
                int rows = BATCH - r0;
                if (rows > chunkRows) rows = chunkRows;
                k_hist<<<dim3(rows), dim3(256), 0, stream>>>(words, histC, r0);
                int mtiles = rows / 256;
                int S = pick_S(mtiles);
                int KT = (KPAD / 64) / S;
                k_gemm<0><<<dim3(mtiles * 4 * S), dim3(512), 0, stream>>>(
                    histC, W1b, hid + (size_t)r0 * HIDDEN, nullptr, KT, mtiles);
            }
        }
        k_out<<<dim3(BATCH / 8), dim3(256), 0, stream>>>(hid, W2T, b2, out);
    }
}